// Round 11
// baseline (91.335 us; speedup 1.0000x reference)
//
#include <hip/hip_runtime.h>

typedef unsigned short u16;
typedef __bf16 bf16x8 __attribute__((ext_vector_type(8)));
typedef float f32x16 __attribute__((ext_vector_type(16)));

union B8 { bf16x8 v; u16 s[8]; unsigned u[4]; uint4 u4; };

__device__ __forceinline__ unsigned cvtpk(float a, float b) {
    unsigned r;
    asm("v_cvt_pk_bf16_f32 %0, %1, %2" : "=v"(r) : "v"(a), "v"(b));
    return r;
}
__device__ __forceinline__ float ex2(float x) { return __builtin_amdgcn_exp2f(x); }
__device__ __forceinline__ void swap32(unsigned &a, unsigned &b) {
    asm("v_permlane32_swap_b32 %0, %1" : "+v"(a), "+v"(b));
}
__device__ __forceinline__ B8 load_w8(const float* __restrict__ p, float s) {
    float4 lo = ((const float4*)p)[0];
    float4 hi = ((const float4*)p)[1];
    B8 r;
    r.u[0] = cvtpk(lo.x * s, lo.y * s);
    r.u[1] = cvtpk(lo.z * s, lo.w * s);
    r.u[2] = cvtpk(hi.x * s, hi.y * s);
    r.u[3] = cvtpk(hi.z * s, hi.w * s);
    return r;
}
__device__ __forceinline__ f32x16 mfma32(const B8 a, const B8 b, f32x16 c) {
    return __builtin_amdgcn_mfma_f32_32x32x16_bf16(a.v, b.v, c, 0, 0, 0);
}
// K LDS: [512 tok][32 ck] u16, 4x16B slots per row XOR-swizzled by (tok>>1)&3
__device__ __forceinline__ int kidx(int row, int sl) {
    return row * 32 + (((sl ^ (row >> 1)) & 3) << 3);
}
// D-regs (rows (r&3)+8*(r>>2)+4*h5) -> two B-fragments (k-chunks of 16) via cvtpk+permlane
__device__ __forceinline__ void build_b(const float* p, B8& b0, B8& b1) {
    unsigned c0 = cvtpk(p[0], p[1]),   c1 = cvtpk(p[2], p[3]);
    unsigned c2 = cvtpk(p[4], p[5]),   c3 = cvtpk(p[6], p[7]);
    unsigned c4 = cvtpk(p[8], p[9]),   c5 = cvtpk(p[10], p[11]);
    unsigned c6 = cvtpk(p[12], p[13]), c7 = cvtpk(p[14], p[15]);
    swap32(c0, c2); swap32(c1, c3); swap32(c4, c6); swap32(c5, c7);
    b0.u[0] = c0; b0.u[1] = c1; b0.u[2] = c2; b0.u[3] = c3;
    b1.u[0] = c4; b1.u[1] = c5; b1.u[2] = c6; b1.u[3] = c7;
}

// LDS (u16 idx): K [512][32] @0 (32768B) | V [64][520] @16384 (66560B) | X [256][72] @49664 (36864B)
#define VOFF 16384
#define XOFF 49664
#define NSM  68096

__global__ __launch_bounds__(512, 1)
void psab_fused(const float* __restrict__ x,
                const float* __restrict__ wk, const float* __restrict__ bk,
                const float* __restrict__ wv, const float* __restrict__ bv,
                const float* __restrict__ wo, const float* __restrict__ bo,
                float* __restrict__ out)
{
    __shared__ __align__(16) u16 smem[NSM];
    const int t    = threadIdx.x;
    const int lane = t & 63;
    const int wid  = t >> 6;       // wave = hb row of the window
    const int cl   = lane & 31;
    const int h5   = lane >> 5;

    // 256 blocks (1/CU): block handles windows n0 = xcd*64 + idx*2 and n0+1 (sd-adjacent)
    const int bid = blockIdx.x;
    const int xcd = bid & 7;
    const int idx = bid >> 3;              // 0..31
    const int n0  = xcd * 64 + idx * 2;
    const int sh = n0 >> 6, sw = (n0 >> 3) & 7, sd0 = n0 & 7;
    const size_t bv0 = (size_t)(sh * 8) * 4096 + (size_t)(sw * 8) * 64 + (size_t)(sd0 * 8);

    const float WSC = 0.50506330f;   // sqrt(log2(e)/sqrt(32)) folded into K weights
    const f32x16 z16 = {0,0,0,0,0,0,0,0,0,0,0,0,0,0,0,0};

    // ---- X staging: chunk = 256 tok (4 hb x 8 wb x 8 db); thread (cS,r2) ----
    const int cS = t & 63;
    const int r2 = t >> 6;
    float4 L4[4], H4[4];
#define LDXW(BV, cc)                                                                         \
    _Pragma("unroll")                                                                        \
    for (int i = 0; i < 4; ++i) {                                                            \
        const float* gp = x + (size_t)cS * 262144 + (BV) + ((cc) * 4 + i) * 4096 + r2 * 64;  \
        L4[i] = ((const float4*)gp)[0];                                                      \
        H4[i] = ((const float4*)gp)[1];                                                      \
    }
#define STX()                                                                                \
    _Pragma("unroll")                                                                        \
    for (int i = 0; i < 4; ++i) {                                                            \
        unsigned a0 = cvtpk(L4[i].x, L4[i].y), a1 = cvtpk(L4[i].z, L4[i].w);                 \
        unsigned a2 = cvtpk(H4[i].x, H4[i].y), a3 = cvtpk(H4[i].z, H4[i].w);                 \
        u16* xp = &smem[XOFF + (i * 64 + r2 * 8) * 72 + cS];                                 \
        xp[0 * 72] = (u16)a0; xp[1 * 72] = (u16)(a0 >> 16);                                  \
        xp[2 * 72] = (u16)a1; xp[3 * 72] = (u16)(a1 >> 16);                                  \
        xp[4 * 72] = (u16)a2; xp[5 * 72] = (u16)(a2 >> 16);                                  \
        xp[6 * 72] = (u16)a3; xp[7 * 72] = (u16)(a3 >> 16);                                  \
    }

    LDXW(bv0, 0)
    STX()                                      // stage win0 chunk0 (visible after loop-top barrier)

    for (int w = 0; w < 2; ++w) {
        const size_t base_vox = bv0 + (size_t)(8 * w);   // n0 -> n0+1 is sd+1
        __syncthreads();                       // (1) X c0 visible; K/V overwrite safe (w>0)

        // ---- per-window weights (w=1 reload hits L2) ----
        B8 wkA[4], wvB[2][4];
#pragma unroll
        for (int kc = 0; kc < 4; ++kc)
            wkA[kc] = load_w8(wk + cl * 64 + kc * 16 + h5 * 8, WSC);
#pragma unroll
        for (int nb = 0; nb < 2; ++nb)
#pragma unroll
            for (int kc = 0; kc < 4; ++kc)
                wvB[nb][kc] = load_w8(wv + (nb * 32 + cl) * 64 + kc * 16 + h5 * 8, 1.0f);
        float bkv[16];
#pragma unroll
        for (int r = 0; r < 16; ++r)
            bkv[r] = bk[(r & 3) + 8 * (r >> 2) + 4 * h5] * WSC;
        const float vbias[2] = { bv[cl], bv[32 + cl] };

        LDXW(base_vox, 1)                      // prefetch chunk1 under proj-chunk0 compute

#pragma unroll
        for (int cc = 0; cc < 2; ++cc) {
            const int tokb = cc * 256 + wid * 32;
            B8 ax[4];
#pragma unroll
            for (int kc = 0; kc < 4; ++kc)
                ax[kc].u4 = *(const uint4*)&smem[XOFF + (wid * 32 + cl) * 72 + kc * 16 + h5 * 8];
            // K proj, swapped operands: D col = tok = cl, rows = ck -> 4 packed uint2 stores
            f32x16 kd = mfma32(wkA[0], ax[0], z16);
            kd = mfma32(wkA[1], ax[1], kd);
            kd = mfma32(wkA[2], ax[2], kd);
            kd = mfma32(wkA[3], ax[3], kd);
            const int trow = tokb + cl;
#pragma unroll
            for (int g = 0; g < 4; ++g) {
                uint2 pk;
                pk.x = cvtpk(kd[4 * g + 0] + bkv[4 * g + 0], kd[4 * g + 1] + bkv[4 * g + 1]);
                pk.y = cvtpk(kd[4 * g + 2] + bkv[4 * g + 2], kd[4 * g + 3] + bkv[4 * g + 3]);
                *(uint2*)&smem[kidx(trow, g) + 4 * h5] = pk;
            }
            // V proj: D col = cv, rows = tok -> V^T[cv][tok] packed uint2
#pragma unroll
            for (int nb = 0; nb < 2; ++nb) {
                f32x16 vd = mfma32(ax[0], wvB[nb][0], z16);
                vd = mfma32(ax[1], wvB[nb][1], vd);
                vd = mfma32(ax[2], wvB[nb][2], vd);
                vd = mfma32(ax[3], wvB[nb][3], vd);
                const int cv = nb * 32 + cl;
                const float vbx = vbias[nb];
#pragma unroll
                for (int rq = 0; rq < 4; ++rq) {
                    uint2 pk;
                    pk.x = cvtpk(vd[rq * 4 + 0] + vbx, vd[rq * 4 + 1] + vbx);
                    pk.y = cvtpk(vd[rq * 4 + 2] + vbx, vd[rq * 4 + 3] + vbx);
                    *(uint2*)&smem[VOFF + cv * 520 + tokb + rq * 8 + 4 * h5] = pk;
                }
            }
            if (cc == 0) {
                __syncthreads();               // (2) X c0 readers done
                STX()
                __syncthreads();               // (3) X c1 visible
            }
        }
        __syncthreads();                       // (4) K/V complete

        // ---- attention: wave owns q = wid*64 + qb*32 + cl; 2-stage reg pipeline ----
        B8 qB[2][2];
#pragma unroll
        for (int qb = 0; qb < 2; ++qb)
#pragma unroll
            for (int kc = 0; kc < 2; ++kc)
                qB[qb][kc].u4 = *(const uint4*)&smem[kidx(wid * 64 + qb * 32 + cl, 2 * kc + h5)];

        B8 ones;
        ones.u[0] = 0x3f803f80u; ones.u[1] = 0x3f803f80u;
        ones.u[2] = 0x3f803f80u; ones.u[3] = 0x3f803f80u;

        f32x16 ctx00 = z16, ctx01 = z16, ctx10 = z16, ctx11 = z16;  // ctx[qb][cvb]
        f32x16 lacc0 = z16, lacc1 = z16;                            // row-sum via ones-MFMA

#define LOADF(P, M0)                                                                          \
        P##k0.u4  = *(const uint4*)&smem[kidx((M0) + cl, h5)];                                \
        P##k1.u4  = *(const uint4*)&smem[kidx((M0) + cl, 2 + h5)];                            \
        P##v00.u4 = *(const uint4*)&smem[VOFF + cl * 520 + (M0) + h5 * 8];                    \
        P##v01.u4 = *(const uint4*)&smem[VOFF + cl * 520 + (M0) + 16 + h5 * 8];               \
        P##v10.u4 = *(const uint4*)&smem[VOFF + (32 + cl) * 520 + (M0) + h5 * 8];             \
        P##v11.u4 = *(const uint4*)&smem[VOFF + (32 + cl) * 520 + (M0) + 16 + h5 * 8];

#define SM(sv, lac, c0, c1, P)                                                                \
        {                                                                                     \
            float p[16];                                                                      \
            _Pragma("unroll")                                                                 \
            for (int i2 = 0; i2 < 16; ++i2) p[i2] = ex2(sv[i2]);                              \
            B8 pb0, pb1;                                                                      \
            build_b(p, pb0, pb1);                                                             \
            lac = mfma32(ones, pb0, lac);                                                     \
            lac = mfma32(ones, pb1, lac);                                                     \
            c0 = mfma32(P##v00, pb0, c0);                                                     \
            c0 = mfma32(P##v01, pb1, c0);                                                     \
            c1 = mfma32(P##v10, pb0, c1);                                                     \
            c1 = mfma32(P##v11, pb1, c1);                                                     \
        }

#define COMPUTE(P)                                                                            \
        {                                                                                     \
            f32x16 s0 = mfma32(P##k0, qB[0][0], z16); s0 = mfma32(P##k1, qB[0][1], s0);       \
            f32x16 s1 = mfma32(P##k0, qB[1][0], z16); s1 = mfma32(P##k1, qB[1][1], s1);       \
            SM(s0, lacc0, ctx00, ctx01, P)                                                    \
            SM(s1, lacc1, ctx10, ctx11, P)                                                    \
        }

        B8 fAk0, fAk1, fAv00, fAv01, fAv10, fAv11;
        B8 fBk0, fBk1, fBv00, fBv01, fBv10, fBv11;
        LOADF(fA, 0)
#pragma unroll 1
        for (int cp = 0; cp < 8; ++cp) {
            const int m1 = cp * 64 + 32;
            LOADF(fB, m1)                      // issue next frags before computing current
            COMPUTE(fA)
            if (cp < 7) {
                const int m2 = cp * 64 + 64;
                LOADF(fA, m2)
            }
            COMPUTE(fB)
        }

        const float inv0 = 1.0f / lacc0[0];
        const float inv1 = 1.0f / lacc1[0];

        if (w == 0) { LDXW(bv0 + 8, 0) }       // issue next window's X c0: hides under epilogue

        // out-proj A-frags + ctx -> B-frags (registers only)
        B8 aw[2][4];
#pragma unroll
        for (int cob = 0; cob < 2; ++cob)
#pragma unroll
            for (int kc = 0; kc < 4; ++kc)
                aw[cob][kc] = load_w8(wo + (cob * 32 + cl) * 64 + kc * 16 + h5 * 8, 1.0f);

        float pn[16];
        B8 cq0[4], cq1[4];
#pragma unroll
        for (int i = 0; i < 16; ++i) pn[i] = ctx00[i] * inv0;
        build_b(pn, cq0[0], cq0[1]);
#pragma unroll
        for (int i = 0; i < 16; ++i) pn[i] = ctx01[i] * inv0;
        build_b(pn, cq0[2], cq0[3]);
#pragma unroll
        for (int i = 0; i < 16; ++i) pn[i] = ctx10[i] * inv1;
        build_b(pn, cq1[0], cq1[1]);
#pragma unroll
        for (int i = 0; i < 16; ++i) pn[i] = ctx11[i] * inv1;
        build_b(pn, cq1[2], cq1[3]);

        // bias as rank-1 MFMA: A = splat(bo[co-row]), B = splat(bf16(1/16))
        B8 abo[2], ones16;
        {
            unsigned b0 = cvtpk(bo[cl], bo[cl]);
            unsigned b1 = cvtpk(bo[32 + cl], bo[32 + cl]);
            abo[0].u[0] = b0; abo[0].u[1] = b0; abo[0].u[2] = b0; abo[0].u[3] = b0;
            abo[1].u[0] = b1; abo[1].u[1] = b1; abo[1].u[2] = b1; abo[1].u[3] = b1;
            ones16.u[0] = 0x3d803d80u; ones16.u[1] = 0x3d803d80u;
            ones16.u[2] = 0x3d803d80u; ones16.u[3] = 0x3d803d80u;
        }

        // ---- direct global stores from accumulators ----
        float* ob = out + base_vox;
        const int voxb = wid * 4096 + (cl >> 3) * 64 + (cl & 7) + h5 * 1048576;
#pragma unroll
        for (int cob = 0; cob < 2; ++cob) {
            f32x16 od0 = mfma32(aw[cob][0], cq0[0], z16);
            od0 = mfma32(aw[cob][1], cq0[1], od0);
            od0 = mfma32(aw[cob][2], cq0[2], od0);
            od0 = mfma32(aw[cob][3], cq0[3], od0);
            od0 = mfma32(abo[cob], ones16, od0);
            f32x16 od1 = mfma32(aw[cob][0], cq1[0], z16);
            od1 = mfma32(aw[cob][1], cq1[1], od1);
            od1 = mfma32(aw[cob][2], cq1[2], od1);
            od1 = mfma32(aw[cob][3], cq1[3], od1);
            od1 = mfma32(abo[cob], ones16, od1);
#pragma unroll
            for (int r = 0; r < 16; ++r) {
                const int cop = cob * 32 + (r & 3) + 8 * (r >> 2);   // + 4*h5 via voxb
                ob[(size_t)cop * 262144 + voxb]       = od0[r];
                ob[(size_t)cop * 262144 + voxb + 256] = od1[r];
            }
        }

        if (w == 0) { STX() }                  // stage next window's X c0 (X has no readers now)
    }
}

extern "C" void kernel_launch(void* const* d_in, const int* in_sizes, int n_in,
                              void* d_out, int out_size, void* d_ws, size_t ws_size,
                              hipStream_t stream) {
    const float* x  = (const float*)d_in[0];
    const float* wk = (const float*)d_in[1];
    const float* bk = (const float*)d_in[2];
    const float* wv = (const float*)d_in[3];
    const float* bv = (const float*)d_in[4];
    const float* wo = (const float*)d_in[5];
    const float* bo = (const float*)d_in[6];
    float* o = (float*)d_out;
    psab_fused<<<dim3(256), dim3(512), 0, stream>>>(x, wk, bk, wv, bv, wo, bo, o);
}

// Round 13
// 69.835 us; speedup vs baseline: 1.3079x; 1.3079x over previous
//
#include <hip/hip_runtime.h>

typedef unsigned short u16;
typedef __bf16 bf16x8 __attribute__((ext_vector_type(8)));
typedef float f32x16 __attribute__((ext_vector_type(16)));

union B8 { bf16x8 v; u16 s[8]; unsigned u[4]; uint4 u4; };

__device__ __forceinline__ unsigned cvtpk(float a, float b) {
    unsigned r;
    asm("v_cvt_pk_bf16_f32 %0, %1, %2" : "=v"(r) : "v"(a), "v"(b));
    return r;
}
__device__ __forceinline__ float ex2(float x) { return __builtin_amdgcn_exp2f(x); }
__device__ __forceinline__ void swap32(unsigned &a, unsigned &b) {
    asm("v_permlane32_swap_b32 %0, %1" : "+v"(a), "+v"(b));
}
__device__ __forceinline__ B8 load_w8(const float* __restrict__ p, float s) {
    float4 lo = ((const float4*)p)[0];
    float4 hi = ((const float4*)p)[1];
    B8 r;
    r.u[0] = cvtpk(lo.x * s, lo.y * s);
    r.u[1] = cvtpk(lo.z * s, lo.w * s);
    r.u[2] = cvtpk(hi.x * s, hi.y * s);
    r.u[3] = cvtpk(hi.z * s, hi.w * s);
    return r;
}
__device__ __forceinline__ f32x16 mfma32(const B8 a, const B8 b, f32x16 c) {
    return __builtin_amdgcn_mfma_f32_32x32x16_bf16(a.v, b.v, c, 0, 0, 0);
}
// K LDS: [512 tok][32 ck] u16, 4x16B slots per row XOR-swizzled by (tok>>1)&3
__device__ __forceinline__ int kidx(int row, int sl) {
    return row * 32 + (((sl ^ (row >> 1)) & 3) << 3);
}
// D-regs (rows (r&3)+8*(r>>2)+4*h5) -> two B-fragments (k-chunks of 16) via cvtpk+permlane
__device__ __forceinline__ void build_b(const float* p, B8& b0, B8& b1) {
    unsigned c0 = cvtpk(p[0], p[1]),   c1 = cvtpk(p[2], p[3]);
    unsigned c2 = cvtpk(p[4], p[5]),   c3 = cvtpk(p[6], p[7]);
    unsigned c4 = cvtpk(p[8], p[9]),   c5 = cvtpk(p[10], p[11]);
    unsigned c6 = cvtpk(p[12], p[13]), c7 = cvtpk(p[14], p[15]);
    swap32(c0, c2); swap32(c1, c3); swap32(c4, c6); swap32(c5, c7);
    b0.u[0] = c0; b0.u[1] = c1; b0.u[2] = c2; b0.u[3] = c3;
    b1.u[0] = c4; b1.u[1] = c5; b1.u[2] = c6; b1.u[3] = c7;
}

// LDS (u16 idx): K [512][32] @0 (32768B) | V [64][520] @16384 (66560B) | X [256][72] @49664 (36864B)
#define VOFF 16384
#define XOFF 49664
#define NSM  68096

__global__ __launch_bounds__(512, 1)
void psab_fused(const float* __restrict__ x,
                const float* __restrict__ wk, const float* __restrict__ bk,
                const float* __restrict__ wv, const float* __restrict__ bv,
                const float* __restrict__ wo, const float* __restrict__ bo,
                float* __restrict__ out)
{
    __shared__ __align__(16) u16 smem[NSM];
    const int t    = threadIdx.x;
    const int lane = t & 63;
    const int wid  = t >> 6;       // wave = hb row of the window
    const int cl   = lane & 31;
    const int h5   = lane >> 5;

    const int bid = blockIdx.x;
    const int n   = (bid & 7) * 64 + (bid >> 3);   // XCD-bijective swizzle
    const int sh = n >> 6, sw = (n >> 3) & 7, sd = n & 7;
    const size_t base_vox = (size_t)(sh * 8) * 4096 + (size_t)(sw * 8) * 64 + (size_t)(sd * 8);

    const float WSC = 0.50506330f;   // sqrt(log2(e)/sqrt(32)) folded into K weights

    B8 wkA[4], wvB[2][4];
#pragma unroll
    for (int kc = 0; kc < 4; ++kc)
        wkA[kc] = load_w8(wk + cl * 64 + kc * 16 + h5 * 8, WSC);
#pragma unroll
    for (int nb = 0; nb < 2; ++nb)
#pragma unroll
        for (int kc = 0; kc < 4; ++kc)
            wvB[nb][kc] = load_w8(wv + (nb * 32 + cl) * 64 + kc * 16 + h5 * 8, 1.0f);
    float bkv[16];
#pragma unroll
    for (int r = 0; r < 16; ++r)
        bkv[r] = bk[(r & 3) + 8 * (r >> 2) + 4 * h5] * WSC;
    const float vbias[2] = { bv[cl], bv[32 + cl] };

    const f32x16 z16 = {0,0,0,0,0,0,0,0,0,0,0,0,0,0,0,0};

    // ---- X staging: 2 chunks x 256 tok (4 hb x 8 wb x 8 db); thread (cS,r2) ----
    const int cS = t & 63;
    const int r2 = t >> 6;
    float4 L4[4], H4[4];
#define LDX(cc)                                                                              \
    _Pragma("unroll")                                                                        \
    for (int i = 0; i < 4; ++i) {                                                            \
        const float* gp = x + (size_t)cS * 262144 + base_vox + ((cc) * 4 + i) * 4096 + r2 * 64; \
        L4[i] = ((const float4*)gp)[0];                                                      \
        H4[i] = ((const float4*)gp)[1];                                                      \
    }
#define STX()                                                                                \
    _Pragma("unroll")                                                                        \
    for (int i = 0; i < 4; ++i) {                                                            \
        unsigned a0 = cvtpk(L4[i].x, L4[i].y), a1 = cvtpk(L4[i].z, L4[i].w);                 \
        unsigned a2 = cvtpk(H4[i].x, H4[i].y), a3 = cvtpk(H4[i].z, H4[i].w);                 \
        u16* xp = &smem[XOFF + (i * 64 + r2 * 8) * 72 + cS];                                 \
        xp[0 * 72] = (u16)a0; xp[1 * 72] = (u16)(a0 >> 16);                                  \
        xp[2 * 72] = (u16)a1; xp[3 * 72] = (u16)(a1 >> 16);                                  \
        xp[4 * 72] = (u16)a2; xp[5 * 72] = (u16)(a2 >> 16);                                  \
        xp[6 * 72] = (u16)a3; xp[7 * 72] = (u16)(a3 >> 16);                                  \
    }

    LDX(0)
    STX()
    LDX(1)                                    // issue chunk1 loads before the barrier
    __syncthreads();                          // (1) X0 visible

#pragma unroll
    for (int cc = 0; cc < 2; ++cc) {
        const int tokb = cc * 256 + wid * 32;
        B8 ax[4];
#pragma unroll
        for (int kc = 0; kc < 4; ++kc)
            ax[kc].u4 = *(const uint4*)&smem[XOFF + (wid * 32 + cl) * 72 + kc * 16 + h5 * 8];
        // K proj, swapped operands: D col = tok = cl, rows = ck -> 4 packed uint2 stores
        f32x16 kd = mfma32(wkA[0], ax[0], z16);
        kd = mfma32(wkA[1], ax[1], kd);
        kd = mfma32(wkA[2], ax[2], kd);
        kd = mfma32(wkA[3], ax[3], kd);
        const int trow = tokb + cl;
#pragma unroll
        for (int g = 0; g < 4; ++g) {
            uint2 pk;
            pk.x = cvtpk(kd[4 * g + 0] + bkv[4 * g + 0], kd[4 * g + 1] + bkv[4 * g + 1]);
            pk.y = cvtpk(kd[4 * g + 2] + bkv[4 * g + 2], kd[4 * g + 3] + bkv[4 * g + 3]);
            *(uint2*)&smem[kidx(trow, g) + 4 * h5] = pk;
        }
        // V proj: D col = cv, rows = tok -> V^T[cv][tok] packed uint2
#pragma unroll
        for (int nb = 0; nb < 2; ++nb) {
            f32x16 vd = mfma32(ax[0], wvB[nb][0], z16);
            vd = mfma32(ax[1], wvB[nb][1], vd);
            vd = mfma32(ax[2], wvB[nb][2], vd);
            vd = mfma32(ax[3], wvB[nb][3], vd);
            const int cv = nb * 32 + cl;
            const float vb = vbias[nb];
#pragma unroll
            for (int rq = 0; rq < 4; ++rq) {
                uint2 pk;
                pk.x = cvtpk(vd[rq * 4 + 0] + vb, vd[rq * 4 + 1] + vb);
                pk.y = cvtpk(vd[rq * 4 + 2] + vb, vd[rq * 4 + 3] + vb);
                *(uint2*)&smem[VOFF + cv * 520 + tokb + rq * 8 + 4 * h5] = pk;
            }
        }
        if (cc == 0) {
            __syncthreads();                  // (2) X0 readers done
            STX()
            __syncthreads();                  // (3) X1 visible
        }
    }
    __syncthreads();                          // (4) K/V complete

    // ---- attention: wave owns q = wid*64 + qb*32 + cl; 3-slot pipeline (load/QK/SMPV) ----
    B8 qB[2][2];
#pragma unroll
    for (int qb = 0; qb < 2; ++qb)
#pragma unroll
        for (int kc = 0; kc < 2; ++kc)
            qB[qb][kc].u4 = *(const uint4*)&smem[kidx(wid * 64 + qb * 32 + cl, 2 * kc + h5)];

    // epilogue weights hoisted here: their load latency hides under the attention loop
    B8 aw[2][4];
#pragma unroll
    for (int cob = 0; cob < 2; ++cob)
#pragma unroll
        for (int kc = 0; kc < 4; ++kc)
            aw[cob][kc] = load_w8(wo + (cob * 32 + cl) * 64 + kc * 16 + h5 * 8, 1.0f);
    B8 abo[2], ones16;
    {
        unsigned b0 = cvtpk(bo[cl], bo[cl]);
        unsigned b1 = cvtpk(bo[32 + cl], bo[32 + cl]);
        abo[0].u[0] = b0; abo[0].u[1] = b0; abo[0].u[2] = b0; abo[0].u[3] = b0;
        abo[1].u[0] = b1; abo[1].u[1] = b1; abo[1].u[2] = b1; abo[1].u[3] = b1;
        ones16.u[0] = 0x3d803d80u; ones16.u[1] = 0x3d803d80u;
        ones16.u[2] = 0x3d803d80u; ones16.u[3] = 0x3d803d80u;
    }

    B8 ones;
    ones.u[0] = 0x3f803f80u; ones.u[1] = 0x3f803f80u;
    ones.u[2] = 0x3f803f80u; ones.u[3] = 0x3f803f80u;

    f32x16 ctx00 = z16, ctx01 = z16, ctx10 = z16, ctx11 = z16;  // ctx[qb][cvb]
    f32x16 lacc0 = z16, lacc1 = z16;                            // row-sum via ones-MFMA

#define LOADF(P, M0)                                                                          \
    P##k0.u4  = *(const uint4*)&smem[kidx((M0) + cl, h5)];                                    \
    P##k1.u4  = *(const uint4*)&smem[kidx((M0) + cl, 2 + h5)];                                \
    P##v00.u4 = *(const uint4*)&smem[VOFF + cl * 520 + (M0) + h5 * 8];                        \
    P##v01.u4 = *(const uint4*)&smem[VOFF + cl * 520 + (M0) + 16 + h5 * 8];                   \
    P##v10.u4 = *(const uint4*)&smem[VOFF + (32 + cl) * 520 + (M0) + h5 * 8];                 \
    P##v11.u4 = *(const uint4*)&smem[VOFF + (32 + cl) * 520 + (M0) + 16 + h5 * 8];

#define QKONLY(P, S0, S1)                                                                     \
    S0 = mfma32(P##k0, qB[0][0], z16); S0 = mfma32(P##k1, qB[0][1], S0);                      \
    S1 = mfma32(P##k0, qB[1][0], z16); S1 = mfma32(P##k1, qB[1][1], S1);

#define SM(sv, lac, c0, c1, P)                                                                \
    {                                                                                         \
        float p[16];                                                                          \
        _Pragma("unroll")                                                                     \
        for (int i2 = 0; i2 < 16; ++i2) p[i2] = ex2(sv[i2]);                                  \
        B8 pb0, pb1;                                                                          \
        build_b(p, pb0, pb1);                                                                 \
        lac = mfma32(ones, pb0, lac);                                                         \
        lac = mfma32(ones, pb1, lac);                                                         \
        c0 = mfma32(P##v00, pb0, c0);                                                         \
        c0 = mfma32(P##v01, pb1, c0);                                                         \
        c1 = mfma32(P##v10, pb0, c1);                                                         \
        c1 = mfma32(P##v11, pb1, c1);                                                         \
    }

#define SMPV(S0, S1, P)                                                                       \
    SM(S0, lacc0, ctx00, ctx01, P)                                                            \
    SM(S1, lacc1, ctx10, ctx11, P)

    B8 fAk0, fAk1, fAv00, fAv01, fAv10, fAv11;
    B8 fBk0, fBk1, fBv00, fBv01, fBv10, fBv11;
    f32x16 sA0, sA1, sB0, sB1;

    LOADF(fA, 0)
    QKONLY(fA, sA0, sA1)                       // prologue stall only
#pragma unroll 1
    for (int cp = 0; cp < 8; ++cp) {
        LOADF(fB, cp * 64 + 32)                // issue odd-chunk loads
        SMPV(sA0, sA1, fA)                     // softmax+PV even chunk (covers fB latency)
        QKONLY(fB, sB0, sB1)                   // fB k-frags landed during SMPV
        if (cp < 7) { LOADF(fA, cp * 64 + 64) } // issue next even-chunk loads
        SMPV(sB0, sB1, fB)                     // covers fA latency + QK(fB) latency
        if (cp < 7) { QKONLY(fA, sA0, sA1) }   // QK for next even chunk, ahead of its SMPV
    }

    const float inv0 = 1.0f / lacc0[0];
    const float inv1 = 1.0f / lacc1[0];

    float pn[16];
    B8 cq0[4], cq1[4];   // B-frags per qb over k=cv chunks 0..3
#pragma unroll
    for (int i = 0; i < 16; ++i) pn[i] = ctx00[i] * inv0;
    build_b(pn, cq0[0], cq0[1]);
#pragma unroll
    for (int i = 0; i < 16; ++i) pn[i] = ctx01[i] * inv0;
    build_b(pn, cq0[2], cq0[3]);
#pragma unroll
    for (int i = 0; i < 16; ++i) pn[i] = ctx10[i] * inv1;
    build_b(pn, cq1[0], cq1[1]);
#pragma unroll
    for (int i = 0; i < 16; ++i) pn[i] = ctx11[i] * inv1;
    build_b(pn, cq1[2], cq1[3]);

    // ---- direct global stores from accumulators (no LDS round-trip, no barrier) ----
    float* ob = out + base_vox;
    const int voxb = wid * 4096 + (cl >> 3) * 64 + (cl & 7) + h5 * 1048576;   // qb=0; qb=1 -> +256
#pragma unroll
    for (int cob = 0; cob < 2; ++cob) {
        f32x16 od0 = mfma32(aw[cob][0], cq0[0], z16);
        od0 = mfma32(aw[cob][1], cq0[1], od0);
        od0 = mfma32(aw[cob][2], cq0[2], od0);
        od0 = mfma32(aw[cob][3], cq0[3], od0);
        od0 = mfma32(abo[cob], ones16, od0);
        f32x16 od1 = mfma32(aw[cob][0], cq1[0], z16);
        od1 = mfma32(aw[cob][1], cq1[1], od1);
        od1 = mfma32(aw[cob][2], cq1[2], od1);
        od1 = mfma32(aw[cob][3], cq1[3], od1);
        od1 = mfma32(abo[cob], ones16, od1);
#pragma unroll
        for (int r = 0; r < 16; ++r) {
            const int cop = cob * 32 + (r & 3) + 8 * (r >> 2);   // + 4*h5 via voxb
            ob[(size_t)cop * 262144 + voxb]       = od0[r];
            ob[(size_t)cop * 262144 + voxb + 256] = od1[r];
        }
    }
}

extern "C" void kernel_launch(void* const* d_in, const int* in_sizes, int n_in,
                              void* d_out, int out_size, void* d_ws, size_t ws_size,
                              hipStream_t stream) {
    const float* x  = (const float*)d_in[0];
    const float* wk = (const float*)d_in[1];
    const float* bk = (const float*)d_in[2];
    const float* wv = (const float*)d_in[3];
    const float* bv = (const float*)d_in[4];
    const float* wo = (const float*)d_in[5];
    const float* bo = (const float*)d_in[6];
    float* o = (float*)d_out;
    psab_fused<<<dim3(512), dim3(512), 0, stream>>>(x, wk, bk, wv, bv, wo, bo, o);
}

// Round 14
// 68.864 us; speedup vs baseline: 1.3263x; 1.0141x over previous
//
#include <hip/hip_runtime.h>

typedef unsigned short u16;
typedef __bf16 bf16x8 __attribute__((ext_vector_type(8)));
typedef float f32x16 __attribute__((ext_vector_type(16)));

union B8 { bf16x8 v; u16 s[8]; unsigned u[4]; uint4 u4; };

__device__ __forceinline__ unsigned cvtpk(float a, float b) {
    unsigned r;
    asm("v_cvt_pk_bf16_f32 %0, %1, %2" : "=v"(r) : "v"(a), "v"(b));
    return r;
}
__device__ __forceinline__ float ex2(float x) { return __builtin_amdgcn_exp2f(x); }
__device__ __forceinline__ void swap32(unsigned &a, unsigned &b) {
    asm("v_permlane32_swap_b32 %0, %1" : "+v"(a), "+v"(b));
}
__device__ __forceinline__ B8 load_w8(const float* __restrict__ p, float s) {
    float4 lo = ((const float4*)p)[0];
    float4 hi = ((const float4*)p)[1];
    B8 r;
    r.u[0] = cvtpk(lo.x * s, lo.y * s);
    r.u[1] = cvtpk(lo.z * s, lo.w * s);
    r.u[2] = cvtpk(hi.x * s, hi.y * s);
    r.u[3] = cvtpk(hi.z * s, hi.w * s);
    return r;
}
__device__ __forceinline__ f32x16 mfma32(const B8 a, const B8 b, f32x16 c) {
    return __builtin_amdgcn_mfma_f32_32x32x16_bf16(a.v, b.v, c, 0, 0, 0);
}
// K LDS: [512 tok][32 ck] u16, 4x16B slots per row XOR-swizzled by (tok>>1)&3
__device__ __forceinline__ int kidx(int row, int sl) {
    return row * 32 + (((sl ^ (row >> 1)) & 3) << 3);
}
// D-regs (rows (r&3)+8*(r>>2)+4*h5) -> two B-fragments (k-chunks of 16) via cvtpk+permlane
__device__ __forceinline__ void build_b(const float* p, B8& b0, B8& b1) {
    unsigned c0 = cvtpk(p[0], p[1]),   c1 = cvtpk(p[2], p[3]);
    unsigned c2 = cvtpk(p[4], p[5]),   c3 = cvtpk(p[6], p[7]);
    unsigned c4 = cvtpk(p[8], p[9]),   c5 = cvtpk(p[10], p[11]);
    unsigned c6 = cvtpk(p[12], p[13]), c7 = cvtpk(p[14], p[15]);
    swap32(c0, c2); swap32(c1, c3); swap32(c4, c6); swap32(c5, c7);
    b0.u[0] = c0; b0.u[1] = c1; b0.u[2] = c2; b0.u[3] = c3;
    b1.u[0] = c4; b1.u[1] = c5; b1.u[2] = c6; b1.u[3] = c7;
}

// LDS (u16 idx): K [512][32] @0 (32768B) | V [64][520] @16384 (66560B) | X [256][72] @49664 (36864B)
#define VOFF 16384
#define XOFF 49664
#define NSM  68096

__global__ __launch_bounds__(512, 1)
void psab_fused(const float* __restrict__ x,
                const float* __restrict__ wk, const float* __restrict__ bk,
                const float* __restrict__ wv, const float* __restrict__ bv,
                const float* __restrict__ wo, const float* __restrict__ bo,
                float* __restrict__ out)
{
    __shared__ __align__(16) u16 smem[NSM];
    const int t    = threadIdx.x;
    const int lane = t & 63;
    const int wid  = t >> 6;       // wave = hb row of the window
    const int cl   = lane & 31;
    const int h5   = lane >> 5;

    const int bid = blockIdx.x;
    const int n   = (bid & 7) * 64 + (bid >> 3);   // XCD-bijective swizzle
    const int sh = n >> 6, sw = (n >> 3) & 7, sd = n & 7;
    const size_t base_vox = (size_t)(sh * 8) * 4096 + (size_t)(sw * 8) * 64 + (size_t)(sd * 8);

    const float WSC = 0.50506330f;   // sqrt(log2(e)/sqrt(32)) folded into K weights

    B8 wkA[4], wvB[2][4];
#pragma unroll
    for (int kc = 0; kc < 4; ++kc)
        wkA[kc] = load_w8(wk + cl * 64 + kc * 16 + h5 * 8, WSC);
#pragma unroll
    for (int nb = 0; nb < 2; ++nb)
#pragma unroll
        for (int kc = 0; kc < 4; ++kc)
            wvB[nb][kc] = load_w8(wv + (nb * 32 + cl) * 64 + kc * 16 + h5 * 8, 1.0f);
    float bkv[16];
#pragma unroll
    for (int r = 0; r < 16; ++r)
        bkv[r] = bk[(r & 3) + 8 * (r >> 2) + 4 * h5] * WSC;
    const float vbias[2] = { bv[cl], bv[32 + cl] };

    const f32x16 z16 = {0,0,0,0,0,0,0,0,0,0,0,0,0,0,0,0};

    // ---- X staging: 2 chunks x 256 tok (4 hb x 8 wb x 8 db); thread (cS,r2) ----
    const int cS = t & 63;
    const int r2 = t >> 6;
    float4 L4[4], H4[4];
#define LDX(cc)                                                                              \
    _Pragma("unroll")                                                                        \
    for (int i = 0; i < 4; ++i) {                                                            \
        const float* gp = x + (size_t)cS * 262144 + base_vox + ((cc) * 4 + i) * 4096 + r2 * 64; \
        L4[i] = ((const float4*)gp)[0];                                                      \
        H4[i] = ((const float4*)gp)[1];                                                      \
    }
#define STX()                                                                                \
    _Pragma("unroll")                                                                        \
    for (int i = 0; i < 4; ++i) {                                                            \
        unsigned a0 = cvtpk(L4[i].x, L4[i].y), a1 = cvtpk(L4[i].z, L4[i].w);                 \
        unsigned a2 = cvtpk(H4[i].x, H4[i].y), a3 = cvtpk(H4[i].z, H4[i].w);                 \
        u16* xp = &smem[XOFF + (i * 64 + r2 * 8) * 72 + cS];                                 \
        xp[0 * 72] = (u16)a0; xp[1 * 72] = (u16)(a0 >> 16);                                  \
        xp[2 * 72] = (u16)a1; xp[3 * 72] = (u16)(a1 >> 16);                                  \
        xp[4 * 72] = (u16)a2; xp[5 * 72] = (u16)(a2 >> 16);                                  \
        xp[6 * 72] = (u16)a3; xp[7 * 72] = (u16)(a3 >> 16);                                  \
    }

    LDX(0)
    STX()
    __syncthreads();                          // (1) X0 visible
    LDX(1)                                    // prefetch chunk1 under proj-chunk0 compute

#pragma unroll
    for (int cc = 0; cc < 2; ++cc) {
        const int tokb = cc * 256 + wid * 32;
        B8 ax[4];
#pragma unroll
        for (int kc = 0; kc < 4; ++kc)
            ax[kc].u4 = *(const uint4*)&smem[XOFF + (wid * 32 + cl) * 72 + kc * 16 + h5 * 8];
        // K proj, swapped operands: D col = tok = cl, rows = ck -> 4 packed uint2 stores
        f32x16 kd = mfma32(wkA[0], ax[0], z16);
        kd = mfma32(wkA[1], ax[1], kd);
        kd = mfma32(wkA[2], ax[2], kd);
        kd = mfma32(wkA[3], ax[3], kd);
        const int trow = tokb + cl;
#pragma unroll
        for (int g = 0; g < 4; ++g) {
            uint2 pk;
            pk.x = cvtpk(kd[4 * g + 0] + bkv[4 * g + 0], kd[4 * g + 1] + bkv[4 * g + 1]);
            pk.y = cvtpk(kd[4 * g + 2] + bkv[4 * g + 2], kd[4 * g + 3] + bkv[4 * g + 3]);
            *(uint2*)&smem[kidx(trow, g) + 4 * h5] = pk;
        }
        // V proj: D col = cv, rows = tok -> V^T[cv][tok] packed uint2
#pragma unroll
        for (int nb = 0; nb < 2; ++nb) {
            f32x16 vd = mfma32(ax[0], wvB[nb][0], z16);
            vd = mfma32(ax[1], wvB[nb][1], vd);
            vd = mfma32(ax[2], wvB[nb][2], vd);
            vd = mfma32(ax[3], wvB[nb][3], vd);
            const int cv = nb * 32 + cl;
            const float vb = vbias[nb];
#pragma unroll
            for (int rq = 0; rq < 4; ++rq) {
                uint2 pk;
                pk.x = cvtpk(vd[rq * 4 + 0] + vb, vd[rq * 4 + 1] + vb);
                pk.y = cvtpk(vd[rq * 4 + 2] + vb, vd[rq * 4 + 3] + vb);
                *(uint2*)&smem[VOFF + cv * 520 + tokb + rq * 8 + 4 * h5] = pk;
            }
        }
        if (cc == 0) {
            __syncthreads();                  // (2) X0 readers done
            STX()
            __syncthreads();                  // (3) X1 visible
        }
    }
    __syncthreads();                          // (4) K/V complete

    // ---- attention: wave owns q = wid*64 + qb*32 + cl; explicit 2-stage reg pipeline ----
    B8 qB[2][2];
#pragma unroll
    for (int qb = 0; qb < 2; ++qb)
#pragma unroll
        for (int kc = 0; kc < 2; ++kc)
            qB[qb][kc].u4 = *(const uint4*)&smem[kidx(wid * 64 + qb * 32 + cl, 2 * kc + h5)];

    B8 ones;
    ones.u[0] = 0x3f803f80u; ones.u[1] = 0x3f803f80u;
    ones.u[2] = 0x3f803f80u; ones.u[3] = 0x3f803f80u;

    f32x16 ctx00 = z16, ctx01 = z16, ctx10 = z16, ctx11 = z16;  // ctx[qb][cvb]
    f32x16 lacc0 = z16, lacc1 = z16;                            // row-sum via ones-MFMA

#define LOADF(P, M0)                                                                          \
    P##k0.u4  = *(const uint4*)&smem[kidx((M0) + cl, h5)];                                    \
    P##k1.u4  = *(const uint4*)&smem[kidx((M0) + cl, 2 + h5)];                                \
    P##v00.u4 = *(const uint4*)&smem[VOFF + cl * 520 + (M0) + h5 * 8];                        \
    P##v01.u4 = *(const uint4*)&smem[VOFF + cl * 520 + (M0) + 16 + h5 * 8];                   \
    P##v10.u4 = *(const uint4*)&smem[VOFF + (32 + cl) * 520 + (M0) + h5 * 8];                 \
    P##v11.u4 = *(const uint4*)&smem[VOFF + (32 + cl) * 520 + (M0) + 16 + h5 * 8];

#define SM(sv, lac, c0, c1, P)                                                                \
    {                                                                                         \
        float p[16];                                                                          \
        _Pragma("unroll")                                                                     \
        for (int i2 = 0; i2 < 16; ++i2) p[i2] = ex2(sv[i2]);                                  \
        B8 pb0, pb1;                                                                          \
        build_b(p, pb0, pb1);                                                                 \
        lac = mfma32(ones, pb0, lac);                                                         \
        lac = mfma32(ones, pb1, lac);                                                         \
        c0 = mfma32(P##v00, pb0, c0);                                                         \
        c0 = mfma32(P##v01, pb1, c0);                                                         \
        c1 = mfma32(P##v10, pb0, c1);                                                         \
        c1 = mfma32(P##v11, pb1, c1);                                                         \
    }

#define COMPUTE(P)                                                                            \
    {                                                                                         \
        f32x16 s0 = mfma32(P##k0, qB[0][0], z16); s0 = mfma32(P##k1, qB[0][1], s0);           \
        f32x16 s1 = mfma32(P##k0, qB[1][0], z16); s1 = mfma32(P##k1, qB[1][1], s1);           \
        SM(s0, lacc0, ctx00, ctx01, P)                                                        \
        SM(s1, lacc1, ctx10, ctx11, P)                                                        \
    }

    B8 fAk0, fAk1, fAv00, fAv01, fAv10, fAv11;
    B8 fBk0, fBk1, fBv00, fBv01, fBv10, fBv11;
    LOADF(fA, 0)
#pragma unroll 1
    for (int cp = 0; cp < 8; ++cp) {
        const int m1 = cp * 64 + 32;
        LOADF(fB, m1)                          // issue next frags before computing current
        COMPUTE(fA)
        if (cp < 7) {
            const int m2 = cp * 64 + 64;
            LOADF(fA, m2)
        }
        COMPUTE(fB)
    }

    const float inv0 = 1.0f / lacc0[0];
    const float inv1 = 1.0f / lacc1[0];

    // out-proj A-frags + ctx -> B-frags (registers only)
    B8 aw[2][4];
#pragma unroll
    for (int cob = 0; cob < 2; ++cob)
#pragma unroll
        for (int kc = 0; kc < 4; ++kc)
            aw[cob][kc] = load_w8(wo + (cob * 32 + cl) * 64 + kc * 16 + h5 * 8, 1.0f);

    float pn[16];
    B8 cq0[4], cq1[4];   // B-frags per qb over k=cv chunks 0..3
#pragma unroll
    for (int i = 0; i < 16; ++i) pn[i] = ctx00[i] * inv0;
    build_b(pn, cq0[0], cq0[1]);
#pragma unroll
    for (int i = 0; i < 16; ++i) pn[i] = ctx01[i] * inv0;
    build_b(pn, cq0[2], cq0[3]);
#pragma unroll
    for (int i = 0; i < 16; ++i) pn[i] = ctx10[i] * inv1;
    build_b(pn, cq1[0], cq1[1]);
#pragma unroll
    for (int i = 0; i < 16; ++i) pn[i] = ctx11[i] * inv1;
    build_b(pn, cq1[2], cq1[3]);

    // bias as rank-1 MFMA: A = splat(bo[co-row]), B = splat(bf16(1/16)); sum_k = bo
    B8 abo[2], ones16;
    {
        unsigned b0 = cvtpk(bo[cl], bo[cl]);
        unsigned b1 = cvtpk(bo[32 + cl], bo[32 + cl]);
        abo[0].u[0] = b0; abo[0].u[1] = b0; abo[0].u[2] = b0; abo[0].u[3] = b0;
        abo[1].u[0] = b1; abo[1].u[1] = b1; abo[1].u[2] = b1; abo[1].u[3] = b1;
        ones16.u[0] = 0x3d803d80u; ones16.u[1] = 0x3d803d80u;
        ones16.u[2] = 0x3d803d80u; ones16.u[3] = 0x3d803d80u;
    }

    // ---- direct global stores from accumulators (no LDS round-trip, no barrier) ----
    float* ob = out + base_vox;
    const int voxb = wid * 4096 + (cl >> 3) * 64 + (cl & 7) + h5 * 1048576;   // qb=0; qb=1 -> +256
#pragma unroll
    for (int cob = 0; cob < 2; ++cob) {
        f32x16 od0 = mfma32(aw[cob][0], cq0[0], z16);
        od0 = mfma32(aw[cob][1], cq0[1], od0);
        od0 = mfma32(aw[cob][2], cq0[2], od0);
        od0 = mfma32(aw[cob][3], cq0[3], od0);
        od0 = mfma32(abo[cob], ones16, od0);
        f32x16 od1 = mfma32(aw[cob][0], cq1[0], z16);
        od1 = mfma32(aw[cob][1], cq1[1], od1);
        od1 = mfma32(aw[cob][2], cq1[2], od1);
        od1 = mfma32(aw[cob][3], cq1[3], od1);
        od1 = mfma32(abo[cob], ones16, od1);
#pragma unroll
        for (int r = 0; r < 16; ++r) {
            const int cop = cob * 32 + (r & 3) + 8 * (r >> 2);   // + 4*h5 via voxb
            ob[(size_t)cop * 262144 + voxb]       = od0[r];
            ob[(size_t)cop * 262144 + voxb + 256] = od1[r];
        }
    }
}

extern "C" void kernel_launch(void* const* d_in, const int* in_sizes, int n_in,
                              void* d_out, int out_size, void* d_ws, size_t ws_size,
                              hipStream_t stream) {
    const float* x  = (const float*)d_in[0];
    const float* wk = (const float*)d_in[1];
    const float* bk = (const float*)d_in[2];
    const float* wv = (const float*)d_in[3];
    const float* bv = (const float*)d_in[4];
    const float* wo = (const float*)d_in[5];
    const float* bo = (const float*)d_in[6];
    float* o = (float*)d_out;
    psab_fused<<<dim3(512), dim3(512), 0, stream>>>(x, wk, bk, wv, bv, wo, bo, o);
}